// Round 1
// baseline (580.132 us; speedup 1.0000x reference)
//
#include <hip/hip_runtime.h>
#include <math.h>

typedef __attribute__((ext_vector_type(8))) short short8;
typedef __attribute__((ext_vector_type(4))) float float4v;
typedef __attribute__((ext_vector_type(4))) unsigned short ushort4v;
typedef unsigned short u16;

#define NB 64
#define NN 2048
#define FD 128
#define UD 64
#define KT 384

__device__ __forceinline__ u16 f2bf(float f) {
    unsigned int u = __float_as_uint(f);
    u += 0x7fffu + ((u >> 16) & 1u);
    return (u16)(u >> 16);
}
__device__ __forceinline__ float bf2f(u16 s) {
    return __uint_as_float(((unsigned int)s) << 16);
}
__device__ __forceinline__ float sigmoidf_(float x) {
    return 1.0f / (1.0f + expf(-x));
}

// ---------------------------------------------------------------- rownorm
__global__ void k_rownorm(const float* __restrict__ adj, float* __restrict__ d_inv) {
    int m = blockIdx.x;
    const float4v* row = (const float4v*)(adj + (size_t)m * NN);
    float s = 0.f;
    for (int i = threadIdx.x; i < NN / 4; i += 256) {
        float4v v = row[i];
        s += v.x + v.y + v.z + v.w;
    }
    __shared__ float red[4];
    for (int off = 32; off; off >>= 1) s += __shfl_down(s, off, 64);
    if ((threadIdx.x & 63) == 0) red[threadIdx.x >> 6] = s;
    __syncthreads();
    if (threadIdx.x == 0) {
        float t = red[0] + red[1] + red[2] + red[3] + 1.0f;
        d_inv[m] = 1.0f / t;
    }
}

// ---------------------------------------------------------------- adjT (bf16, transposed + normalized)
// adjT[n][m] = (adj[m][n] + (m==n)) * d_inv[m]
__global__ void k_adjT(const float* __restrict__ adj, const float* __restrict__ d_inv,
                       u16* __restrict__ adjT) {
    __shared__ u16 T[64 * 72];
    int m0 = blockIdx.x * 64;
    int n0 = blockIdx.y * 64;
    int t = threadIdx.x;
    for (int p = 0; p < 4; ++p) {
        int idx = t + 256 * p;     // 0..1023
        int i  = idx >> 4;         // row 0..63
        int n4 = idx & 15;         // col chunk
        int m = m0 + i;
        float4v v = *(const float4v*)(adj + (size_t)m * NN + n0 + n4 * 4);
        float di = d_inv[m];
        float vv[4] = {v.x, v.y, v.z, v.w};
#pragma unroll
        for (int j = 0; j < 4; ++j) {
            int n = n0 + n4 * 4 + j;
            float a = vv[j] + ((m == n) ? 1.0f : 0.0f);
            T[(n4 * 4 + j) * 72 + i] = f2bf(a * di);
        }
    }
    __syncthreads();
    for (int p = 0; p < 2; ++p) {
        int idx = t + 256 * p;     // 0..511
        int n  = idx >> 3;         // 0..63
        int m8 = (idx & 7) * 8;
        *(short8*)(adjT + (size_t)(n0 + n) * NN + m0 + m8) = *(const short8*)(T + n * 72 + m8);
    }
}

// ---------------------------------------------------------------- W reorder: Wt[o][kd*128+f] = W[f*3+kd][o]
__global__ void k_reorderW(const float* __restrict__ W, u16* __restrict__ Wt, int OD) {
    int idx = blockIdx.x * 256 + threadIdx.x;
    if (idx >= KT * OD) return;
    int o  = idx % OD;
    int kp = idx / OD;
    int kd = kp >> 7, f = kp & 127;
    Wt[(size_t)o * KT + kp] = f2bf(W[(size_t)(f * 3 + kd) * OD + o]);
}

// ---------------------------------------------------------------- xcat: X0c[(b*128+f)][m] = concat(x,h)
__global__ void k_xcat(const float* __restrict__ x, const float* __restrict__ h,
                       u16* __restrict__ X0c) {
    __shared__ u16 T[128 * 136];
    int m0 = blockIdx.x * 128;
    int b  = blockIdx.y;
    int t = threadIdx.x;
    const float* srcs[2] = { x + (size_t)b * (NN * 64), h + (size_t)b * (NN * 64) };
    for (int s = 0; s < 2; ++s) {
        const float* src = srcs[s];
        for (int p = 0; p < 8; ++p) {
            int idx = t + 256 * p;   // 0..2047
            int mi = idx >> 4;       // 0..127
            int f4 = idx & 15;       // 0..15
            float4v v = *(const float4v*)(src + (size_t)(m0 + mi) * 64 + f4 * 4);
            float vv[4] = {v.x, v.y, v.z, v.w};
#pragma unroll
            for (int j = 0; j < 4; ++j)
                T[(s * 64 + f4 * 4 + j) * 136 + mi] = f2bf(vv[j]);
        }
    }
    __syncthreads();
    for (int p = 0; p < 8; ++p) {
        int idx = t + 256 * p;
        int f  = idx >> 4;
        int m8 = (idx & 15) * 8;
        *(short8*)(X0c + ((size_t)(b * FD + f)) * NN + m0 + m8) = *(const short8*)(T + f * 136 + m8);
    }
}

// ---------------------------------------------------------------- big GEMM: Cc = bf16(alpha*A@B - Sub)
// A: adjT [2048][2048] row-major. Bc: [NC][2048] (c-row, m-contig). Cc: [NC][2048] (c-row, n-contig).
// mode 0: Cc = A@Bc ; mode 1: Cc = 2*A@Bc - Sub
__global__ __launch_bounds__(256)
void k_gemm_big(const u16* __restrict__ A, const u16* __restrict__ Bc,
                u16* __restrict__ Cc, const u16* __restrict__ Sub, int mode) {
    __shared__ u16 As[128 * 40];
    __shared__ u16 Bs[128 * 40];
    int c0 = blockIdx.x * 128;
    int n0 = blockIdx.y * 128;
    int t = threadIdx.x;
    int wave = t >> 6, lane = t & 63;
    int wr = (wave >> 1) * 64, wc = (wave & 1) * 64;
    int lr = lane & 15, q = lane >> 4;
    float4v acc[4][4];
#pragma unroll
    for (int i = 0; i < 4; ++i)
#pragma unroll
        for (int j = 0; j < 4; ++j) { acc[i][j].x = 0.f; acc[i][j].y = 0.f; acc[i][j].z = 0.f; acc[i][j].w = 0.f; }

    for (int k0 = 0; k0 < 2048; k0 += 32) {
#pragma unroll
        for (int p = 0; p < 2; ++p) {
            int ch = t + 256 * p;         // 0..511
            int i  = ch >> 2;
            int k8 = (ch & 3) * 8;
            *(short8*)(As + i * 40 + k8) = *(const short8*)(A  + (size_t)(n0 + i) * 2048 + k0 + k8);
            *(short8*)(Bs + i * 40 + k8) = *(const short8*)(Bc + (size_t)(c0 + i) * 2048 + k0 + k8);
        }
        __syncthreads();
        short8 af[4], bfr[4];
#pragma unroll
        for (int i = 0; i < 4; ++i) af[i]  = *(const short8*)(As + (wr + 16 * i + lr) * 40 + q * 8);
#pragma unroll
        for (int j = 0; j < 4; ++j) bfr[j] = *(const short8*)(Bs + (wc + 16 * j + lr) * 40 + q * 8);
#pragma unroll
        for (int i = 0; i < 4; ++i)
#pragma unroll
            for (int j = 0; j < 4; ++j)
                acc[i][j] = __builtin_amdgcn_mfma_f32_16x16x32_bf16(af[i], bfr[j], acc[i][j], 0, 0, 0);
        __syncthreads();
    }
#pragma unroll
    for (int i = 0; i < 4; ++i) {
        int n = n0 + wr + 16 * i + q * 4;
#pragma unroll
        for (int j = 0; j < 4; ++j) {
            int c = c0 + wc + 16 * j + lr;
            float4v v = acc[i][j];
            ushort4v pk;
            if (mode == 1) {
                ushort4v s = *(const ushort4v*)(Sub + (size_t)c * 2048 + n);
#pragma unroll
                for (int r = 0; r < 4; ++r) pk[r] = f2bf(2.f * v[r] - bf2f(s[r]));
            } else {
#pragma unroll
                for (int r = 0; r < 4; ++r) pk[r] = f2bf(v[r]);
            }
            *(ushort4v*)(Cc + (size_t)c * 2048 + n) = pk;
        }
    }
}

// ---------------------------------------------------------------- ru projection (K=384) + sigmoid + r*h / u
__global__ __launch_bounds__(256)
void k_ruW(const u16* __restrict__ X0c, const u16* __restrict__ X1c, const u16* __restrict__ X2c,
           const u16* __restrict__ Wt, const float* __restrict__ bias,
           const float* __restrict__ hx,
           u16* __restrict__ RH0c, float* __restrict__ Utc) {
    __shared__ u16 As[128 * 40];
    __shared__ u16 Bs[128 * 40];
    int rt = blockIdx.x;           // 0..1023
    int b  = rt >> 4;
    int m0 = (rt & 15) * 128;
    int t = threadIdx.x;
    int wave = t >> 6, lane = t & 63;
    int wr = (wave >> 1) * 64, wc = (wave & 1) * 64;
    int lr = lane & 15, q = lane >> 4;
    const u16* Xs[3] = {X0c, X1c, X2c};
    float4v acc[4][4];
#pragma unroll
    for (int i = 0; i < 4; ++i)
#pragma unroll
        for (int j = 0; j < 4; ++j) { acc[i][j].x = 0.f; acc[i][j].y = 0.f; acc[i][j].z = 0.f; acc[i][j].w = 0.f; }

    for (int it = 0; it < 12; ++it) {
        int k0 = it * 32;
        int kd = k0 >> 7, fb = k0 & 127;
        const u16* src = Xs[kd] + ((size_t)(b * FD + fb)) * NN + m0;
#pragma unroll
        for (int p = 0; p < 2; ++p) {
            int ch = t + 256 * p;        // 0..511
            int f  = ch & 31;
            int m8 = (ch >> 5) * 8;      // 0..120
            short8 v = *(const short8*)(src + (size_t)f * NN + m8);
#pragma unroll
            for (int e = 0; e < 8; ++e)
                As[(m8 + e) * 40 + f] = (u16)v[e];
        }
#pragma unroll
        for (int p = 0; p < 2; ++p) {
            int ch = t + 256 * p;
            int o  = ch >> 2;
            int k8 = (ch & 3) * 8;
            *(short8*)(Bs + o * 40 + k8) = *(const short8*)(Wt + (size_t)o * KT + k0 + k8);
        }
        __syncthreads();
        short8 af[4], bfr[4];
#pragma unroll
        for (int i = 0; i < 4; ++i) af[i]  = *(const short8*)(As + (wr + 16 * i + lr) * 40 + q * 8);
#pragma unroll
        for (int j = 0; j < 4; ++j) bfr[j] = *(const short8*)(Bs + (wc + 16 * j + lr) * 40 + q * 8);
#pragma unroll
        for (int i = 0; i < 4; ++i)
#pragma unroll
            for (int j = 0; j < 4; ++j)
                acc[i][j] = __builtin_amdgcn_mfma_f32_16x16x32_bf16(af[i], bfr[j], acc[i][j], 0, 0, 0);
        __syncthreads();
    }
#pragma unroll
    for (int i = 0; i < 4; ++i) {
        int m = m0 + wr + 16 * i + q * 4;
#pragma unroll
        for (int j = 0; j < 4; ++j) {
            int o = wc + 16 * j + lr;
            float bia = bias[o];
            float4v v = acc[i][j];
            if (o < 64) {
                ushort4v pk;
#pragma unroll
                for (int r = 0; r < 4; ++r) {
                    float s = sigmoidf_(v[r] + bia);
                    float hh = hx[(size_t)b * (NN * 64) + (size_t)(m + r) * 64 + o];
                    pk[r] = f2bf(s * hh);
                }
                *(ushort4v*)(RH0c + ((size_t)(b * UD + o)) * NN + m) = pk;
            } else {
                int g = o - 64;
                float4v u;
#pragma unroll
                for (int r = 0; r < 4; ++r) u[r] = sigmoidf_(v[r] + bia);
                *(float4v*)(Utc + ((size_t)(b * UD + g)) * NN + m) = u;
            }
        }
    }
}

// ---------------------------------------------------------------- c projection (K=384) + tanh + final combine
__global__ __launch_bounds__(256)
void k_cW(const u16* __restrict__ X0c, const u16* __restrict__ X1c, const u16* __restrict__ X2c,
          const u16* __restrict__ RH0c, const u16* __restrict__ RH1c, const u16* __restrict__ RH2c,
          const u16* __restrict__ Wt, const float* __restrict__ bias,
          const float* __restrict__ hx, const float* __restrict__ Utc,
          float* __restrict__ out) {
    __shared__ u16 As[256 * 40];
    __shared__ u16 Bs[64 * 40];
    int rt = blockIdx.x;           // 0..511
    int b  = rt >> 3;
    int m0 = (rt & 7) * 256;
    int t = threadIdx.x;
    int wave = t >> 6, lane = t & 63;
    int lr = lane & 15, q = lane >> 4;
    const u16* Xs[3] = {X0c, X1c, X2c};
    const u16* Rs[3] = {RH0c, RH1c, RH2c};
    float4v acc[4][4];
#pragma unroll
    for (int i = 0; i < 4; ++i)
#pragma unroll
        for (int j = 0; j < 4; ++j) { acc[i][j].x = 0.f; acc[i][j].y = 0.f; acc[i][j].z = 0.f; acc[i][j].w = 0.f; }

    for (int it = 0; it < 12; ++it) {
        int k0 = it * 32;
        int kd = k0 >> 7, fb = k0 & 127;
        const u16* src;
        if (fb < 64) src = Xs[kd] + ((size_t)(b * FD + fb)) * NN + m0;
        else         src = Rs[kd] + ((size_t)(b * UD + (fb - 64))) * NN + m0;
#pragma unroll
        for (int p = 0; p < 4; ++p) {
            int ch = t + 256 * p;        // 0..1023
            int f  = ch & 31;
            int m8 = (ch >> 5) * 8;      // 0..248
            short8 v = *(const short8*)(src + (size_t)f * NN + m8);
#pragma unroll
            for (int e = 0; e < 8; ++e)
                As[(m8 + e) * 40 + f] = (u16)v[e];
        }
        {
            int o  = t >> 2;             // 0..63
            int k8 = (t & 3) * 8;
            *(short8*)(Bs + o * 40 + k8) = *(const short8*)(Wt + (size_t)o * KT + k0 + k8);
        }
        __syncthreads();
        short8 af[4], bfr[4];
#pragma unroll
        for (int i = 0; i < 4; ++i) af[i]  = *(const short8*)(As + (64 * wave + 16 * i + lr) * 40 + q * 8);
#pragma unroll
        for (int j = 0; j < 4; ++j) bfr[j] = *(const short8*)(Bs + (16 * j + lr) * 40 + q * 8);
#pragma unroll
        for (int i = 0; i < 4; ++i)
#pragma unroll
            for (int j = 0; j < 4; ++j)
                acc[i][j] = __builtin_amdgcn_mfma_f32_16x16x32_bf16(af[i], bfr[j], acc[i][j], 0, 0, 0);
        __syncthreads();
    }
#pragma unroll
    for (int i = 0; i < 4; ++i) {
        int m = m0 + 64 * wave + 16 * i + q * 4;
#pragma unroll
        for (int j = 0; j < 4; ++j) {
            int o = 16 * j + lr;
            float bia = bias[o];
            float4v v = acc[i][j];
            float4v u = *(const float4v*)(Utc + ((size_t)(b * UD + o)) * NN + m);
#pragma unroll
            for (int r = 0; r < 4; ++r) {
                float c = tanhf(v[r] + bia);
                size_t idx = (size_t)b * (NN * 64) + (size_t)(m + r) * 64 + o;
                float hh = hx[idx];
                out[idx] = u[r] * hh + (1.0f - u[r]) * c;
            }
        }
    }
}

// ---------------------------------------------------------------- launch
extern "C" void kernel_launch(void* const* d_in, const int* in_sizes, int n_in,
                              void* d_out, int out_size, void* d_ws, size_t ws_size,
                              hipStream_t stream) {
    const float* x    = (const float*)d_in[0];
    const float* hx   = (const float*)d_in[1];
    const float* adj  = (const float*)d_in[2];
    const float* W_ru = (const float*)d_in[3];
    const float* b_ru = (const float*)d_in[4];
    const float* W_c  = (const float*)d_in[5];
    const float* b_c  = (const float*)d_in[6];
    float* out = (float*)d_out;

    char* ws = (char*)d_ws;
    size_t off = 0;
    auto alloc = [&](size_t bytes) -> void* {
        void* p = ws + off;
        off += (bytes + 255) & ~(size_t)255;
        return p;
    };
    float* d_inv = (float*)alloc((size_t)NN * 4);
    u16* adjT  = (u16*)alloc((size_t)NN * NN * 2);
    u16* Wt_ru = (u16*)alloc((size_t)FD * KT * 2);
    u16* Wt_c  = (u16*)alloc((size_t)UD * KT * 2);
    u16* X0c = (u16*)alloc((size_t)NB * FD * NN * 2);
    u16* X1c = (u16*)alloc((size_t)NB * FD * NN * 2);
    u16* X2c = (u16*)alloc((size_t)NB * FD * NN * 2);
    u16* RH0c = (u16*)alloc((size_t)NB * UD * NN * 2);
    u16* RH1c = (u16*)alloc((size_t)NB * UD * NN * 2);
    u16* RH2c = (u16*)alloc((size_t)NB * UD * NN * 2);
    float* Utc = (float*)alloc((size_t)NB * UD * NN * 4);

    k_rownorm<<<dim3(NN), dim3(256), 0, stream>>>(adj, d_inv);
    k_adjT<<<dim3(32, 32), dim3(256), 0, stream>>>(adj, d_inv, adjT);
    k_reorderW<<<dim3((KT * FD + 255) / 256), dim3(256), 0, stream>>>(W_ru, Wt_ru, FD);
    k_reorderW<<<dim3((KT * UD + 255) / 256), dim3(256), 0, stream>>>(W_c, Wt_c, UD);
    k_xcat<<<dim3(16, NB), dim3(256), 0, stream>>>(x, hx, X0c);
    // X1 = A @ X0 ; X2 = 2 A @ X1 - X0   (8192 columns)
    k_gemm_big<<<dim3(64, 16), dim3(256), 0, stream>>>(adjT, X0c, X1c, nullptr, 0);
    k_gemm_big<<<dim3(64, 16), dim3(256), 0, stream>>>(adjT, X1c, X2c, X0c, 1);
    // ru = sigmoid(proj) -> RH0 = r*h (bf16), Ut = u (fp32)
    k_ruW<<<dim3(1024), dim3(256), 0, stream>>>(X0c, X1c, X2c, Wt_ru, b_ru, hx, RH0c, Utc);
    // RH1 = A @ RH0 ; RH2 = 2 A @ RH1 - RH0   (4096 columns)
    k_gemm_big<<<dim3(32, 16), dim3(256), 0, stream>>>(adjT, RH0c, RH1c, nullptr, 0);
    k_gemm_big<<<dim3(32, 16), dim3(256), 0, stream>>>(adjT, RH1c, RH2c, RH0c, 1);
    // c = tanh(proj), out = u*h + (1-u)*c
    k_cW<<<dim3(512), dim3(256), 0, stream>>>(X0c, X1c, X2c, RH0c, RH1c, RH2c, Wt_c, b_c, hx, Utc, out);
}

// Round 2
// 568.599 us; speedup vs baseline: 1.0203x; 1.0203x over previous
//
#include <hip/hip_runtime.h>
#include <math.h>

typedef __attribute__((ext_vector_type(8))) short short8;
typedef __attribute__((ext_vector_type(4))) float float4v;
typedef __attribute__((ext_vector_type(4))) unsigned short ushort4v;
typedef unsigned short u16;
typedef unsigned int u32;

#define NB 64
#define NN 2048
#define FD 128
#define UD 64
#define KT 384

__device__ __forceinline__ u16 f2bf(float f) {
    unsigned int u = __float_as_uint(f);
    u += 0x7fffu + ((u >> 16) & 1u);
    return (u16)(u >> 16);
}
__device__ __forceinline__ float bf2f(u16 s) {
    return __uint_as_float(((unsigned int)s) << 16);
}
__device__ __forceinline__ float sigmoidf_(float x) {
    return 1.0f / (1.0f + expf(-x));
}
// async global->LDS, 16B per lane; LDS dest must be wave-uniform base + lane*16
__device__ __forceinline__ void gl2lds16(const u16* g, u16* l) {
    __builtin_amdgcn_global_load_lds((const __attribute__((address_space(1))) unsigned int*)g,
                                     (__attribute__((address_space(3))) unsigned int*)l,
                                     16, 0, 0);
}

// ---------------------------------------------------------------- rownorm
__global__ void k_rownorm(const float* __restrict__ adj, float* __restrict__ d_inv) {
    int m = blockIdx.x;
    const float4v* row = (const float4v*)(adj + (size_t)m * NN);
    float s = 0.f;
    for (int i = threadIdx.x; i < NN / 4; i += 256) {
        float4v v = row[i];
        s += v.x + v.y + v.z + v.w;
    }
    __shared__ float red[4];
    for (int off = 32; off; off >>= 1) s += __shfl_down(s, off, 64);
    if ((threadIdx.x & 63) == 0) red[threadIdx.x >> 6] = s;
    __syncthreads();
    if (threadIdx.x == 0) {
        float t = red[0] + red[1] + red[2] + red[3] + 1.0f;
        d_inv[m] = 1.0f / t;
    }
}

// ---------------------------------------------------------------- adjT (bf16, transposed + normalized)
__global__ void k_adjT(const float* __restrict__ adj, const float* __restrict__ d_inv,
                       u16* __restrict__ adjT) {
    __shared__ u16 T[64 * 72];
    int m0 = blockIdx.x * 64;
    int n0 = blockIdx.y * 64;
    int t = threadIdx.x;
    for (int p = 0; p < 4; ++p) {
        int idx = t + 256 * p;
        int i  = idx >> 4;
        int n4 = idx & 15;
        int m = m0 + i;
        float4v v = *(const float4v*)(adj + (size_t)m * NN + n0 + n4 * 4);
        float di = d_inv[m];
        float vv[4] = {v.x, v.y, v.z, v.w};
#pragma unroll
        for (int j = 0; j < 4; ++j) {
            int n = n0 + n4 * 4 + j;
            float a = vv[j] + ((m == n) ? 1.0f : 0.0f);
            T[(n4 * 4 + j) * 72 + i] = f2bf(a * di);
        }
    }
    __syncthreads();
    for (int p = 0; p < 2; ++p) {
        int idx = t + 256 * p;
        int n  = idx >> 3;
        int m8 = (idx & 7) * 8;
        *(short8*)(adjT + (size_t)(n0 + n) * NN + m0 + m8) = *(const short8*)(T + n * 72 + m8);
    }
}

// ---------------------------------------------------------------- W reorder: Wt[o][kd*128+f] = W[f*3+kd][o]
__global__ void k_reorderW(const float* __restrict__ W, u16* __restrict__ Wt, int OD) {
    int idx = blockIdx.x * 256 + threadIdx.x;
    if (idx >= KT * OD) return;
    int o  = idx % OD;
    int kp = idx / OD;
    int kd = kp >> 7, f = kp & 127;
    Wt[(size_t)o * KT + kp] = f2bf(W[(size_t)(f * 3 + kd) * OD + o]);
}

// ---------------------------------------------------------------- xcat: X0c[(b*128+f)][m] = concat(x,h)
__global__ void k_xcat(const float* __restrict__ x, const float* __restrict__ h,
                       u16* __restrict__ X0c) {
    __shared__ u16 T[128 * 136];
    int m0 = blockIdx.x * 128;
    int b  = blockIdx.y;
    int t = threadIdx.x;
    const float* srcs[2] = { x + (size_t)b * (NN * 64), h + (size_t)b * (NN * 64) };
    for (int s = 0; s < 2; ++s) {
        const float* src = srcs[s];
        for (int p = 0; p < 8; ++p) {
            int idx = t + 256 * p;
            int mi = idx >> 4;
            int f4 = idx & 15;
            float4v v = *(const float4v*)(src + (size_t)(m0 + mi) * 64 + f4 * 4);
            float vv[4] = {v.x, v.y, v.z, v.w};
#pragma unroll
            for (int j = 0; j < 4; ++j)
                T[(s * 64 + f4 * 4 + j) * 136 + mi] = f2bf(vv[j]);
        }
    }
    __syncthreads();
    for (int p = 0; p < 8; ++p) {
        int idx = t + 256 * p;
        int f  = idx >> 4;
        int m8 = (idx & 15) * 8;
        *(short8*)(X0c + ((size_t)(b * FD + f)) * NN + m0 + m8) = *(const short8*)(T + f * 136 + m8);
    }
}

// ---------------------------------------------------------------- big GEMM via global_load_lds staging
// A: adjT [2048][2048]. Bc: [NC][2048] m-contig. Cc: [NC][2048] n-contig.
// mode 0: Cc = A@Bc ; mode 1: Cc = 2*A@Bc - Sub
__global__ __launch_bounds__(256)
void k_gemm_big(const u16* __restrict__ A, const u16* __restrict__ Bc,
                u16* __restrict__ Cc, const u16* __restrict__ Sub, int mode) {
    __shared__ u16 As[128 * 32];   // unpadded: required by global_load_lds lane ordering
    __shared__ u16 Bs[128 * 32];
    int c0 = blockIdx.x * 128;
    int n0 = blockIdx.y * 128;
    int t = threadIdx.x;
    int wave = t >> 6, lane = t & 63;
    int wr = (wave >> 1) * 64, wc = (wave & 1) * 64;
    int lr = lane & 15, q = lane >> 4;

    int r0 = t >> 2;               // row 0..63
    int cc = (t & 3) * 8;          // k-chunk offset (u16)
    const u16* ga0 = A  + (size_t)(n0 + r0) * 2048 + cc;
    const u16* ga1 = A  + (size_t)(n0 + r0 + 64) * 2048 + cc;
    const u16* gb0 = Bc + (size_t)(c0 + r0) * 2048 + cc;
    const u16* gb1 = Bc + (size_t)(c0 + r0 + 64) * 2048 + cc;
    u16* la0 = As + t * 8;  u16* la1 = As + (t + 256) * 8;
    u16* lb0 = Bs + t * 8;  u16* lb1 = Bs + (t + 256) * 8;

    float4v acc[4][4];
#pragma unroll
    for (int i = 0; i < 4; ++i)
#pragma unroll
        for (int j = 0; j < 4; ++j) { acc[i][j].x = 0.f; acc[i][j].y = 0.f; acc[i][j].z = 0.f; acc[i][j].w = 0.f; }

    for (int k0 = 0; k0 < 2048; k0 += 32) {
        gl2lds16(ga0 + k0, la0);
        gl2lds16(ga1 + k0, la1);
        gl2lds16(gb0 + k0, lb0);
        gl2lds16(gb1 + k0, lb1);
        __syncthreads();           // compiler drains vmcnt before s_barrier
        short8 af[4], bfr[4];
#pragma unroll
        for (int i = 0; i < 4; ++i) af[i]  = *(const short8*)(As + (wr + 16 * i + lr) * 32 + q * 8);
#pragma unroll
        for (int j = 0; j < 4; ++j) bfr[j] = *(const short8*)(Bs + (wc + 16 * j + lr) * 32 + q * 8);
#pragma unroll
        for (int i = 0; i < 4; ++i)
#pragma unroll
            for (int j = 0; j < 4; ++j)
                acc[i][j] = __builtin_amdgcn_mfma_f32_16x16x32_bf16(af[i], bfr[j], acc[i][j], 0, 0, 0);
        __syncthreads();
    }
#pragma unroll
    for (int i = 0; i < 4; ++i) {
        int n = n0 + wr + 16 * i + q * 4;
#pragma unroll
        for (int j = 0; j < 4; ++j) {
            int c = c0 + wc + 16 * j + lr;
            float4v v = acc[i][j];
            ushort4v pk;
            if (mode == 1) {
                ushort4v s = *(const ushort4v*)(Sub + (size_t)c * 2048 + n);
#pragma unroll
                for (int r = 0; r < 4; ++r) pk[r] = f2bf(2.f * v[r] - bf2f(s[r]));
            } else {
#pragma unroll
                for (int r = 0; r < 4; ++r) pk[r] = f2bf(v[r]);
            }
            *(ushort4v*)(Cc + (size_t)c * 2048 + n) = pk;
        }
    }
}

// ---------------------------------------------------------------- ru projection (K=384) + sigmoid + r*h / u
__global__ __launch_bounds__(256)
void k_ruW(const u16* __restrict__ X0c, const u16* __restrict__ X1c, const u16* __restrict__ X2c,
           const u16* __restrict__ Wt, const float* __restrict__ bias,
           const float* __restrict__ hx,
           u16* __restrict__ RH0c, float* __restrict__ Utc) {
    __shared__ u16 As[128 * 40];   // padded (scatter-transposed, not global_load_lds)
    __shared__ u16 Bs[128 * 32];   // unpadded (global_load_lds)
    int rt = blockIdx.x;           // 0..1023
    int b  = rt >> 4;
    int m0 = (rt & 15) * 128;
    int t = threadIdx.x;
    int wave = t >> 6, lane = t & 63;
    int wr = (wave >> 1) * 64, wc = (wave & 1) * 64;
    int lr = lane & 15, q = lane >> 4;
    const u16* Xs[3] = {X0c, X1c, X2c};
    int f2 = t & 15;               // feature-pair 0..15  (f = 2*f2, 2*f2+1)
    int m8 = (t >> 4) * 8;         // m-group 0..15 -> m offset
    const u16* gw = Wt + (size_t)(t >> 2) * KT + (t & 3) * 8;
    u16* lw0 = Bs + t * 8;  u16* lw1 = Bs + (t + 256) * 8;
    const u16* gw1 = Wt + (size_t)((t >> 2) + 64) * KT + (t & 3) * 8;

    float4v acc[4][4];
#pragma unroll
    for (int i = 0; i < 4; ++i)
#pragma unroll
        for (int j = 0; j < 4; ++j) { acc[i][j].x = 0.f; acc[i][j].y = 0.f; acc[i][j].z = 0.f; acc[i][j].w = 0.f; }

    for (int it = 0; it < 12; ++it) {
        int k0 = it * 32;
        int kd = k0 >> 7, fb = k0 & 127;
        const u16* src = Xs[kd] + ((size_t)(b * FD + fb)) * NN + m0;
        // W staging (async)
        gl2lds16(gw  + k0, lw0);
        gl2lds16(gw1 + k0, lw1);
        // X transpose-scatter: 2 features packed per u32 write
        short8 v0 = *(const short8*)(src + (size_t)(2 * f2)     * NN + m8);
        short8 v1 = *(const short8*)(src + (size_t)(2 * f2 + 1) * NN + m8);
#pragma unroll
        for (int e = 0; e < 8; ++e)
            *(u32*)(As + (m8 + e) * 40 + 2 * f2) = (u32)(u16)v0[e] | ((u32)(u16)v1[e] << 16);
        __syncthreads();
        short8 af[4], bfr[4];
#pragma unroll
        for (int i = 0; i < 4; ++i) af[i]  = *(const short8*)(As + (wr + 16 * i + lr) * 40 + q * 8);
#pragma unroll
        for (int j = 0; j < 4; ++j) bfr[j] = *(const short8*)(Bs + (wc + 16 * j + lr) * 32 + q * 8);
#pragma unroll
        for (int i = 0; i < 4; ++i)
#pragma unroll
            for (int j = 0; j < 4; ++j)
                acc[i][j] = __builtin_amdgcn_mfma_f32_16x16x32_bf16(af[i], bfr[j], acc[i][j], 0, 0, 0);
        __syncthreads();
    }
#pragma unroll
    for (int i = 0; i < 4; ++i) {
        int m = m0 + wr + 16 * i + q * 4;
#pragma unroll
        for (int j = 0; j < 4; ++j) {
            int o = wc + 16 * j + lr;
            float bia = bias[o];
            float4v v = acc[i][j];
            if (o < 64) {
                ushort4v pk;
#pragma unroll
                for (int r = 0; r < 4; ++r) {
                    float s = sigmoidf_(v[r] + bia);
                    float hh = hx[(size_t)b * (NN * 64) + (size_t)(m + r) * 64 + o];
                    pk[r] = f2bf(s * hh);
                }
                *(ushort4v*)(RH0c + ((size_t)(b * UD + o)) * NN + m) = pk;
            } else {
                int g = o - 64;
                float4v u;
#pragma unroll
                for (int r = 0; r < 4; ++r) u[r] = sigmoidf_(v[r] + bia);
                *(float4v*)(Utc + ((size_t)(b * UD + g)) * NN + m) = u;
            }
        }
    }
}

// ---------------------------------------------------------------- c projection (K=384) + tanh + final combine
__global__ __launch_bounds__(256)
void k_cW(const u16* __restrict__ X0c, const u16* __restrict__ X1c, const u16* __restrict__ X2c,
          const u16* __restrict__ RH0c, const u16* __restrict__ RH1c, const u16* __restrict__ RH2c,
          const u16* __restrict__ Wt, const float* __restrict__ bias,
          const float* __restrict__ hx, const float* __restrict__ Utc,
          float* __restrict__ out) {
    __shared__ u16 As[256 * 40];
    __shared__ u16 Bs[64 * 32];
    int rt = blockIdx.x;           // 0..511
    int b  = rt >> 3;
    int m0 = (rt & 7) * 256;
    int t = threadIdx.x;
    int wave = t >> 6, lane = t & 63;
    int lr = lane & 15, q = lane >> 4;
    const u16* Xs[3] = {X0c, X1c, X2c};
    const u16* Rs[3] = {RH0c, RH1c, RH2c};
    const u16* gw = Wt + (size_t)(t >> 2) * KT + (t & 3) * 8;
    u16* lw = Bs + t * 8;

    float4v acc[4][4];
#pragma unroll
    for (int i = 0; i < 4; ++i)
#pragma unroll
        for (int j = 0; j < 4; ++j) { acc[i][j].x = 0.f; acc[i][j].y = 0.f; acc[i][j].z = 0.f; acc[i][j].w = 0.f; }

    for (int it = 0; it < 12; ++it) {
        int k0 = it * 32;
        int kd = k0 >> 7, fb = k0 & 127;
        const u16* src;
        if (fb < 64) src = Xs[kd] + ((size_t)(b * FD + fb)) * NN + m0;
        else         src = Rs[kd] + ((size_t)(b * UD + (fb - 64))) * NN + m0;
        gl2lds16(gw + k0, lw);
#pragma unroll
        for (int p = 0; p < 2; ++p) {
            int idx = t + 256 * p;       // 0..511
            int f2 = idx & 15;
            int m8 = (idx >> 4) * 8;     // 0..248
            short8 v0 = *(const short8*)(src + (size_t)(2 * f2)     * NN + m8);
            short8 v1 = *(const short8*)(src + (size_t)(2 * f2 + 1) * NN + m8);
#pragma unroll
            for (int e = 0; e < 8; ++e)
                *(u32*)(As + (m8 + e) * 40 + 2 * f2) = (u32)(u16)v0[e] | ((u32)(u16)v1[e] << 16);
        }
        __syncthreads();
        short8 af[4], bfr[4];
#pragma unroll
        for (int i = 0; i < 4; ++i) af[i]  = *(const short8*)(As + (64 * wave + 16 * i + lr) * 40 + q * 8);
#pragma unroll
        for (int j = 0; j < 4; ++j) bfr[j] = *(const short8*)(Bs + (16 * j + lr) * 32 + q * 8);
#pragma unroll
        for (int i = 0; i < 4; ++i)
#pragma unroll
            for (int j = 0; j < 4; ++j)
                acc[i][j] = __builtin_amdgcn_mfma_f32_16x16x32_bf16(af[i], bfr[j], acc[i][j], 0, 0, 0);
        __syncthreads();
    }
#pragma unroll
    for (int i = 0; i < 4; ++i) {
        int m = m0 + 64 * wave + 16 * i + q * 4;
#pragma unroll
        for (int j = 0; j < 4; ++j) {
            int o = 16 * j + lr;
            float bia = bias[o];
            float4v v = acc[i][j];
            float4v u = *(const float4v*)(Utc + ((size_t)(b * UD + o)) * NN + m);
#pragma unroll
            for (int r = 0; r < 4; ++r) {
                float c = tanhf(v[r] + bia);
                size_t idx = (size_t)b * (NN * 64) + (size_t)(m + r) * 64 + o;
                float hh = hx[idx];
                out[idx] = u[r] * hh + (1.0f - u[r]) * c;
            }
        }
    }
}

// ---------------------------------------------------------------- launch
extern "C" void kernel_launch(void* const* d_in, const int* in_sizes, int n_in,
                              void* d_out, int out_size, void* d_ws, size_t ws_size,
                              hipStream_t stream) {
    const float* x    = (const float*)d_in[0];
    const float* hx   = (const float*)d_in[1];
    const float* adj  = (const float*)d_in[2];
    const float* W_ru = (const float*)d_in[3];
    const float* b_ru = (const float*)d_in[4];
    const float* W_c  = (const float*)d_in[5];
    const float* b_c  = (const float*)d_in[6];
    float* out = (float*)d_out;

    char* ws = (char*)d_ws;
    size_t off = 0;
    auto alloc = [&](size_t bytes) -> void* {
        void* p = ws + off;
        off += (bytes + 255) & ~(size_t)255;
        return p;
    };
    float* d_inv = (float*)alloc((size_t)NN * 4);
    u16* adjT  = (u16*)alloc((size_t)NN * NN * 2);
    u16* Wt_ru = (u16*)alloc((size_t)FD * KT * 2);
    u16* Wt_c  = (u16*)alloc((size_t)UD * KT * 2);
    u16* X0c = (u16*)alloc((size_t)NB * FD * NN * 2);
    u16* X1c = (u16*)alloc((size_t)NB * FD * NN * 2);
    u16* X2c = (u16*)alloc((size_t)NB * FD * NN * 2);
    u16* RH0c = (u16*)alloc((size_t)NB * UD * NN * 2);
    u16* RH1c = (u16*)alloc((size_t)NB * UD * NN * 2);
    u16* RH2c = (u16*)alloc((size_t)NB * UD * NN * 2);
    float* Utc = (float*)alloc((size_t)NB * UD * NN * 4);

    k_rownorm<<<dim3(NN), dim3(256), 0, stream>>>(adj, d_inv);
    k_adjT<<<dim3(32, 32), dim3(256), 0, stream>>>(adj, d_inv, adjT);
    k_reorderW<<<dim3((KT * FD + 255) / 256), dim3(256), 0, stream>>>(W_ru, Wt_ru, FD);
    k_reorderW<<<dim3((KT * UD + 255) / 256), dim3(256), 0, stream>>>(W_c, Wt_c, UD);
    k_xcat<<<dim3(16, NB), dim3(256), 0, stream>>>(x, hx, X0c);
    k_gemm_big<<<dim3(64, 16), dim3(256), 0, stream>>>(adjT, X0c, X1c, nullptr, 0);
    k_gemm_big<<<dim3(64, 16), dim3(256), 0, stream>>>(adjT, X1c, X2c, X0c, 1);
    k_ruW<<<dim3(1024), dim3(256), 0, stream>>>(X0c, X1c, X2c, Wt_ru, b_ru, hx, RH0c, Utc);
    k_gemm_big<<<dim3(32, 16), dim3(256), 0, stream>>>(adjT, RH0c, RH1c, nullptr, 0);
    k_gemm_big<<<dim3(32, 16), dim3(256), 0, stream>>>(adjT, RH1c, RH2c, RH0c, 1);
    k_cW<<<dim3(512), dim3(256), 0, stream>>>(X0c, X1c, X2c, RH0c, RH1c, RH2c, Wt_c, b_c, hx, Utc, out);
}

// Round 3
// 520.115 us; speedup vs baseline: 1.1154x; 1.0932x over previous
//
#include <hip/hip_runtime.h>
#include <math.h>

typedef __attribute__((ext_vector_type(8))) short short8;
typedef __attribute__((ext_vector_type(4))) float float4v;
typedef __attribute__((ext_vector_type(4))) unsigned short ushort4v;
typedef unsigned short u16;
typedef unsigned int u32;

#define NB 64
#define NN 2048
#define FD 128
#define UD 64
#define KT 384

__device__ __forceinline__ u16 f2bf(float f) {
    unsigned int u = __float_as_uint(f);
    u += 0x7fffu + ((u >> 16) & 1u);
    return (u16)(u >> 16);
}
__device__ __forceinline__ float bf2f(u16 s) {
    return __uint_as_float(((unsigned int)s) << 16);
}
__device__ __forceinline__ float sigmoidf_(float x) {
    return 1.0f / (1.0f + expf(-x));
}
// async global->LDS, 16B per lane; LDS dest must be wave-uniform base + lane*16
__device__ __forceinline__ void gl2lds16(const u16* g, u16* l) {
    __builtin_amdgcn_global_load_lds((const __attribute__((address_space(1))) unsigned int*)g,
                                     (__attribute__((address_space(3))) unsigned int*)l,
                                     16, 0, 0);
}

// ---------------------------------------------------------------- rownorm
__global__ void k_rownorm(const float* __restrict__ adj, float* __restrict__ d_inv) {
    int m = blockIdx.x;
    const float4v* row = (const float4v*)(adj + (size_t)m * NN);
    float s = 0.f;
    for (int i = threadIdx.x; i < NN / 4; i += 256) {
        float4v v = row[i];
        s += v.x + v.y + v.z + v.w;
    }
    __shared__ float red[4];
    for (int off = 32; off; off >>= 1) s += __shfl_down(s, off, 64);
    if ((threadIdx.x & 63) == 0) red[threadIdx.x >> 6] = s;
    __syncthreads();
    if (threadIdx.x == 0) {
        float t = red[0] + red[1] + red[2] + red[3] + 1.0f;
        d_inv[m] = 1.0f / t;
    }
}

// ---------------------------------------------------------------- adjT (bf16, transposed + normalized)
__global__ void k_adjT(const float* __restrict__ adj, const float* __restrict__ d_inv,
                       u16* __restrict__ adjT) {
    __shared__ u16 T[64 * 72];
    int m0 = blockIdx.x * 64;
    int n0 = blockIdx.y * 64;
    int t = threadIdx.x;
    for (int p = 0; p < 4; ++p) {
        int idx = t + 256 * p;
        int i  = idx >> 4;
        int n4 = idx & 15;
        int m = m0 + i;
        float4v v = *(const float4v*)(adj + (size_t)m * NN + n0 + n4 * 4);
        float di = d_inv[m];
        float vv[4] = {v.x, v.y, v.z, v.w};
#pragma unroll
        for (int j = 0; j < 4; ++j) {
            int n = n0 + n4 * 4 + j;
            float a = vv[j] + ((m == n) ? 1.0f : 0.0f);
            T[(n4 * 4 + j) * 72 + i] = f2bf(a * di);
        }
    }
    __syncthreads();
    for (int p = 0; p < 2; ++p) {
        int idx = t + 256 * p;
        int n  = idx >> 3;
        int m8 = (idx & 7) * 8;
        *(short8*)(adjT + (size_t)(n0 + n) * NN + m0 + m8) = *(const short8*)(T + n * 72 + m8);
    }
}

// ---------------------------------------------------------------- W reorder: Wt[o][kd*128+f] = W[f*3+kd][o]
__global__ void k_reorderW(const float* __restrict__ W, u16* __restrict__ Wt, int OD) {
    int idx = blockIdx.x * 256 + threadIdx.x;
    if (idx >= KT * OD) return;
    int o  = idx % OD;
    int kp = idx / OD;
    int kd = kp >> 7, f = kp & 127;
    Wt[(size_t)o * KT + kp] = f2bf(W[(size_t)(f * 3 + kd) * OD + o]);
}

// ---------------------------------------------------------------- xcat: X0c[(b*128+f)][m] = concat(x,h)
__global__ void k_xcat(const float* __restrict__ x, const float* __restrict__ h,
                       u16* __restrict__ X0c) {
    __shared__ u16 T[128 * 136];
    int m0 = blockIdx.x * 128;
    int b  = blockIdx.y;
    int t = threadIdx.x;
    const float* srcs[2] = { x + (size_t)b * (NN * 64), h + (size_t)b * (NN * 64) };
    for (int s = 0; s < 2; ++s) {
        const float* src = srcs[s];
        for (int p = 0; p < 8; ++p) {
            int idx = t + 256 * p;
            int mi = idx >> 4;
            int f4 = idx & 15;
            float4v v = *(const float4v*)(src + (size_t)(m0 + mi) * 64 + f4 * 4);
            float vv[4] = {v.x, v.y, v.z, v.w};
#pragma unroll
            for (int j = 0; j < 4; ++j)
                T[(s * 64 + f4 * 4 + j) * 136 + mi] = f2bf(vv[j]);
        }
    }
    __syncthreads();
    for (int p = 0; p < 8; ++p) {
        int idx = t + 256 * p;
        int f  = idx >> 4;
        int m8 = (idx & 15) * 8;
        *(short8*)(X0c + ((size_t)(b * FD + f)) * NN + m0 + m8) = *(const short8*)(T + f * 136 + m8);
    }
}

// ---------------------------------------------------------------- big GEMM, double-buffered + XCD swizzle
// A: adjT [2048][2048]. Bc: [NC][2048] m-contig. Cc: [NC][2048] n-contig.
// mode 0: Cc = A@Bc ; mode 1: Cc = 2*A@Bc - Sub
// grid: (cBlocks, 16); band = cBlocks/8 c-blocks per XCD
__global__ __launch_bounds__(256)
void k_gemm_big(const u16* __restrict__ A, const u16* __restrict__ Bc,
                u16* __restrict__ Cc, const u16* __restrict__ Sub, int mode, int cBlocks) {
    // 33280 B shared: K-loop uses 2 stages x (A 8KB + B 8KB) = 32768 B; epilogue 128x130 u16
    __shared__ u16 SM[128 * 130];
    u16* A0 = SM;          u16* A1 = SM + 4096;
    u16* B0 = SM + 8192;   u16* B1 = SM + 12288;

    int id = blockIdx.x + cBlocks * blockIdx.y;
    int band = cBlocks >> 3;                 // 8 (big) or 4 (half)
    int g = id & 7;                          // presumed XCD
    int s = id >> 3;
    int cb = g * band + (s % band);
    int nb = s / band;                       // 0..15
    int c0 = cb * 128;
    int n0 = nb * 128;

    int t = threadIdx.x;
    int wave = t >> 6, lane = t & 63;
    int wr = (wave >> 1) * 64, wc = (wave & 1) * 64;
    int lr = lane & 15, q = lane >> 4;

    int r0 = t >> 2;                         // 0..63
    int cc = (t & 3) * 8;
    const u16* ga0 = A  + (size_t)(n0 + r0) * 2048 + cc;
    const u16* ga1 = A  + (size_t)(n0 + r0 + 64) * 2048 + cc;
    const u16* gb0 = Bc + (size_t)(c0 + r0) * 2048 + cc;
    const u16* gb1 = Bc + (size_t)(c0 + r0 + 64) * 2048 + cc;

    float4v acc[4][4];
#pragma unroll
    for (int i = 0; i < 4; ++i)
#pragma unroll
        for (int j = 0; j < 4; ++j) { acc[i][j].x = 0.f; acc[i][j].y = 0.f; acc[i][j].z = 0.f; acc[i][j].w = 0.f; }

    // prologue: prefetch iter 0 into stage 0
    gl2lds16(ga0, A0 + t * 8); gl2lds16(ga1, A0 + (t + 256) * 8);
    gl2lds16(gb0, B0 + t * 8); gl2lds16(gb1, B0 + (t + 256) * 8);

#pragma unroll 2
    for (int it = 0; it < 64; ++it) {
        u16* Ac = (it & 1) ? A1 : A0;
        u16* Bs = (it & 1) ? B1 : B0;
        __syncthreads();                     // stage(it) ready; stage(it-1) reads done
        if (it + 1 < 64) {                   // prefetch next into other stage
            int ko = (it + 1) * 32;
            u16* An = (it & 1) ? A0 : A1;
            u16* Bn = (it & 1) ? B0 : B1;
            gl2lds16(ga0 + ko, An + t * 8); gl2lds16(ga1 + ko, An + (t + 256) * 8);
            gl2lds16(gb0 + ko, Bn + t * 8); gl2lds16(gb1 + ko, Bn + (t + 256) * 8);
        }
        short8 af[4], bfr[4];
#pragma unroll
        for (int i = 0; i < 4; ++i) af[i]  = *(const short8*)(Ac + (wr + 16 * i + lr) * 32 + q * 8);
#pragma unroll
        for (int j = 0; j < 4; ++j) bfr[j] = *(const short8*)(Bs + (wc + 16 * j + lr) * 32 + q * 8);
#pragma unroll
        for (int i = 0; i < 4; ++i)
#pragma unroll
            for (int j = 0; j < 4; ++j)
                acc[i][j] = __builtin_amdgcn_mfma_f32_16x16x32_bf16(af[i], bfr[j], acc[i][j], 0, 0, 0);
    }

    // ---- coalesced epilogue through LDS transpose ----
    __syncthreads();                         // K-loop LDS reads done; SM reusable
#pragma unroll
    for (int i = 0; i < 4; ++i) {
        int nl = wr + 16 * i + q * 4;
#pragma unroll
        for (int j = 0; j < 4; ++j) {
            int cl = wc + 16 * j + lr;
            float4v v = acc[i][j];
            ushort4v pk;
#pragma unroll
            for (int r = 0; r < 4; ++r) pk[r] = f2bf(v[r]);
            *(ushort4v*)(SM + cl * 130 + nl) = pk;
        }
    }
    __syncthreads();
#pragma unroll
    for (int p = 0; p < 2; ++p) {
        int idx = t + 256 * p;               // 0..511
        int cl = idx >> 2;                   // 0..127
        int nc = (idx & 3) * 8;              // 16B chunk within 64B line
        u16* dst = Cc + (size_t)(c0 + cl) * 2048 + n0 + nc;
        const u16* sub = Sub + (size_t)(c0 + cl) * 2048 + n0 + nc;
        const u16* srcl = SM + cl * 130 + nc;
#pragma unroll
        for (int u = 0; u < 4; ++u) {        // 4 chunks, 64B stride
            short8 v = *(const short8*)(srcl + u * 32);
            if (mode == 1) {
                short8 sv = *(const short8*)(sub + u * 32);
                short8 o;
#pragma unroll
                for (int e = 0; e < 8; ++e)
                    o[e] = (short)f2bf(2.f * bf2f((u16)v[e]) - bf2f((u16)sv[e]));
                *(short8*)(dst + u * 32) = o;
            } else {
                *(short8*)(dst + u * 32) = v;
            }
        }
    }
}

// ---------------------------------------------------------------- ru projection (K=384) + sigmoid + r*h / u
__global__ __launch_bounds__(256)
void k_ruW(const u16* __restrict__ X0c, const u16* __restrict__ X1c, const u16* __restrict__ X2c,
           const u16* __restrict__ Wt, const float* __restrict__ bias,
           const float* __restrict__ hx,
           u16* __restrict__ RH0c, float* __restrict__ Utc) {
    __shared__ u16 As[128 * 40];   // padded (scatter-transposed, not global_load_lds)
    __shared__ u16 Bs[128 * 32];   // unpadded (global_load_lds)
    int rt = blockIdx.x;           // 0..1023
    int b  = rt >> 4;
    int m0 = (rt & 15) * 128;
    int t = threadIdx.x;
    int wave = t >> 6, lane = t & 63;
    int wr = (wave >> 1) * 64, wc = (wave & 1) * 64;
    int lr = lane & 15, q = lane >> 4;
    const u16* Xs[3] = {X0c, X1c, X2c};
    int f2 = t & 15;               // feature-pair 0..15  (f = 2*f2, 2*f2+1)
    int m8 = (t >> 4) * 8;         // m-group 0..15 -> m offset
    const u16* gw = Wt + (size_t)(t >> 2) * KT + (t & 3) * 8;
    u16* lw0 = Bs + t * 8;  u16* lw1 = Bs + (t + 256) * 8;
    const u16* gw1 = Wt + (size_t)((t >> 2) + 64) * KT + (t & 3) * 8;

    float4v acc[4][4];
#pragma unroll
    for (int i = 0; i < 4; ++i)
#pragma unroll
        for (int j = 0; j < 4; ++j) { acc[i][j].x = 0.f; acc[i][j].y = 0.f; acc[i][j].z = 0.f; acc[i][j].w = 0.f; }

    for (int it = 0; it < 12; ++it) {
        int k0 = it * 32;
        int kd = k0 >> 7, fb = k0 & 127;
        const u16* src = Xs[kd] + ((size_t)(b * FD + fb)) * NN + m0;
        gl2lds16(gw  + k0, lw0);
        gl2lds16(gw1 + k0, lw1);
        short8 v0 = *(const short8*)(src + (size_t)(2 * f2)     * NN + m8);
        short8 v1 = *(const short8*)(src + (size_t)(2 * f2 + 1) * NN + m8);
#pragma unroll
        for (int e = 0; e < 8; ++e)
            *(u32*)(As + (m8 + e) * 40 + 2 * f2) = (u32)(u16)v0[e] | ((u32)(u16)v1[e] << 16);
        __syncthreads();
        short8 af[4], bfr[4];
#pragma unroll
        for (int i = 0; i < 4; ++i) af[i]  = *(const short8*)(As + (wr + 16 * i + lr) * 40 + q * 8);
#pragma unroll
        for (int j = 0; j < 4; ++j) bfr[j] = *(const short8*)(Bs + (wc + 16 * j + lr) * 32 + q * 8);
#pragma unroll
        for (int i = 0; i < 4; ++i)
#pragma unroll
            for (int j = 0; j < 4; ++j)
                acc[i][j] = __builtin_amdgcn_mfma_f32_16x16x32_bf16(af[i], bfr[j], acc[i][j], 0, 0, 0);
        __syncthreads();
    }
#pragma unroll
    for (int i = 0; i < 4; ++i) {
        int m = m0 + wr + 16 * i + q * 4;
#pragma unroll
        for (int j = 0; j < 4; ++j) {
            int o = wc + 16 * j + lr;
            float bia = bias[o];
            float4v v = acc[i][j];
            if (o < 64) {
                ushort4v pk;
#pragma unroll
                for (int r = 0; r < 4; ++r) {
                    float s = sigmoidf_(v[r] + bia);
                    float hh = hx[(size_t)b * (NN * 64) + (size_t)(m + r) * 64 + o];
                    pk[r] = f2bf(s * hh);
                }
                *(ushort4v*)(RH0c + ((size_t)(b * UD + o)) * NN + m) = pk;
            } else {
                int g = o - 64;
                float4v u;
#pragma unroll
                for (int r = 0; r < 4; ++r) u[r] = sigmoidf_(v[r] + bia);
                *(float4v*)(Utc + ((size_t)(b * UD + g)) * NN + m) = u;
            }
        }
    }
}

// ---------------------------------------------------------------- c projection (K=384) + tanh + final combine
__global__ __launch_bounds__(256)
void k_cW(const u16* __restrict__ X0c, const u16* __restrict__ X1c, const u16* __restrict__ X2c,
          const u16* __restrict__ RH0c, const u16* __restrict__ RH1c, const u16* __restrict__ RH2c,
          const u16* __restrict__ Wt, const float* __restrict__ bias,
          const float* __restrict__ hx, const float* __restrict__ Utc,
          float* __restrict__ out) {
    __shared__ u16 As[256 * 40];
    __shared__ u16 Bs[64 * 32];
    int rt = blockIdx.x;           // 0..511
    int b  = rt >> 3;
    int m0 = (rt & 7) * 256;
    int t = threadIdx.x;
    int wave = t >> 6, lane = t & 63;
    int lr = lane & 15, q = lane >> 4;
    const u16* Xs[3] = {X0c, X1c, X2c};
    const u16* Rs[3] = {RH0c, RH1c, RH2c};
    const u16* gw = Wt + (size_t)(t >> 2) * KT + (t & 3) * 8;
    u16* lw = Bs + t * 8;

    float4v acc[4][4];
#pragma unroll
    for (int i = 0; i < 4; ++i)
#pragma unroll
        for (int j = 0; j < 4; ++j) { acc[i][j].x = 0.f; acc[i][j].y = 0.f; acc[i][j].z = 0.f; acc[i][j].w = 0.f; }

    for (int it = 0; it < 12; ++it) {
        int k0 = it * 32;
        int kd = k0 >> 7, fb = k0 & 127;
        const u16* src;
        if (fb < 64) src = Xs[kd] + ((size_t)(b * FD + fb)) * NN + m0;
        else         src = Rs[kd] + ((size_t)(b * UD + (fb - 64))) * NN + m0;
        gl2lds16(gw + k0, lw);
#pragma unroll
        for (int p = 0; p < 2; ++p) {
            int idx = t + 256 * p;       // 0..511
            int f2 = idx & 15;
            int m8 = (idx >> 4) * 8;     // 0..248
            short8 v0 = *(const short8*)(src + (size_t)(2 * f2)     * NN + m8);
            short8 v1 = *(const short8*)(src + (size_t)(2 * f2 + 1) * NN + m8);
#pragma unroll
            for (int e = 0; e < 8; ++e)
                *(u32*)(As + (m8 + e) * 40 + 2 * f2) = (u32)(u16)v0[e] | ((u32)(u16)v1[e] << 16);
        }
        __syncthreads();
        short8 af[4], bfr[4];
#pragma unroll
        for (int i = 0; i < 4; ++i) af[i]  = *(const short8*)(As + (64 * wave + 16 * i + lr) * 40 + q * 8);
#pragma unroll
        for (int j = 0; j < 4; ++j) bfr[j] = *(const short8*)(Bs + (16 * j + lr) * 32 + q * 8);
#pragma unroll
        for (int i = 0; i < 4; ++i)
#pragma unroll
            for (int j = 0; j < 4; ++j)
                acc[i][j] = __builtin_amdgcn_mfma_f32_16x16x32_bf16(af[i], bfr[j], acc[i][j], 0, 0, 0);
        __syncthreads();
    }
#pragma unroll
    for (int i = 0; i < 4; ++i) {
        int m = m0 + 64 * wave + 16 * i + q * 4;
#pragma unroll
        for (int j = 0; j < 4; ++j) {
            int o = 16 * j + lr;
            float bia = bias[o];
            float4v v = acc[i][j];
            float4v u = *(const float4v*)(Utc + ((size_t)(b * UD + o)) * NN + m);
#pragma unroll
            for (int r = 0; r < 4; ++r) {
                float c = tanhf(v[r] + bia);
                size_t idx = (size_t)b * (NN * 64) + (size_t)(m + r) * 64 + o;
                float hh = hx[idx];
                out[idx] = u[r] * hh + (1.0f - u[r]) * c;
            }
        }
    }
}

// ---------------------------------------------------------------- launch
extern "C" void kernel_launch(void* const* d_in, const int* in_sizes, int n_in,
                              void* d_out, int out_size, void* d_ws, size_t ws_size,
                              hipStream_t stream) {
    const float* x    = (const float*)d_in[0];
    const float* hx   = (const float*)d_in[1];
    const float* adj  = (const float*)d_in[2];
    const float* W_ru = (const float*)d_in[3];
    const float* b_ru = (const float*)d_in[4];
    const float* W_c  = (const float*)d_in[5];
    const float* b_c  = (const float*)d_in[6];
    float* out = (float*)d_out;

    char* ws = (char*)d_ws;
    size_t off = 0;
    auto alloc = [&](size_t bytes) -> void* {
        void* p = ws + off;
        off += (bytes + 255) & ~(size_t)255;
        return p;
    };
    float* d_inv = (float*)alloc((size_t)NN * 4);
    u16* adjT  = (u16*)alloc((size_t)NN * NN * 2);
    u16* Wt_ru = (u16*)alloc((size_t)FD * KT * 2);
    u16* Wt_c  = (u16*)alloc((size_t)UD * KT * 2);
    u16* X0c = (u16*)alloc((size_t)NB * FD * NN * 2);
    u16* X1c = (u16*)alloc((size_t)NB * FD * NN * 2);
    u16* X2c = (u16*)alloc((size_t)NB * FD * NN * 2);
    u16* RH0c = (u16*)alloc((size_t)NB * UD * NN * 2);
    u16* RH1c = (u16*)alloc((size_t)NB * UD * NN * 2);
    u16* RH2c = (u16*)alloc((size_t)NB * UD * NN * 2);
    float* Utc = (float*)alloc((size_t)NB * UD * NN * 4);

    k_rownorm<<<dim3(NN), dim3(256), 0, stream>>>(adj, d_inv);
    k_adjT<<<dim3(32, 32), dim3(256), 0, stream>>>(adj, d_inv, adjT);
    k_reorderW<<<dim3((KT * FD + 255) / 256), dim3(256), 0, stream>>>(W_ru, Wt_ru, FD);
    k_reorderW<<<dim3((KT * UD + 255) / 256), dim3(256), 0, stream>>>(W_c, Wt_c, UD);
    k_xcat<<<dim3(16, NB), dim3(256), 0, stream>>>(x, hx, X0c);
    k_gemm_big<<<dim3(64, 16), dim3(256), 0, stream>>>(adjT, X0c, X1c, X0c, 0, 64);
    k_gemm_big<<<dim3(64, 16), dim3(256), 0, stream>>>(adjT, X1c, X2c, X0c, 1, 64);
    k_ruW<<<dim3(1024), dim3(256), 0, stream>>>(X0c, X1c, X2c, Wt_ru, b_ru, hx, RH0c, Utc);
    k_gemm_big<<<dim3(32, 16), dim3(256), 0, stream>>>(adjT, RH0c, RH1c, RH0c, 0, 32);
    k_gemm_big<<<dim3(32, 16), dim3(256), 0, stream>>>(adjT, RH1c, RH2c, RH0c, 1, 32);
    k_cW<<<dim3(512), dim3(256), 0, stream>>>(X0c, X1c, X2c, RH0c, RH1c, RH2c, Wt_c, b_c, hx, Utc, out);
}